// Round 18
// baseline (2018.366 us; speedup 1.0000x reference)
//
#include <hip/hip_runtime.h>
#include <math.h>

#define Hc 300
#define Ld 64
#define GB 16        // graphs per block (k_rec)
#define GBF 16       // graphs per block (fallback kernel)
#define KT 10        // K tiles of 32 (K padded 300->320)
#define NQ 20        // 16-col q-groups per gate section (N padded 300->320)
#define NT 60        // total n-tiles = 3 sections * NQ
#define PERDIR (2*2*KT*NT*64)   // f16x8 frags per dir = 153600
#define TOTF   (2*PERDIR)       // 307200 total
#define NCW 10       // consumer waves
#define NTH 768      // 10 consumer + 2 producer waves

typedef _Float16 f16x8 __attribute__((ext_vector_type(8)));
typedef float f32x4 __attribute__((ext_vector_type(4)));
typedef unsigned int u32;

#define MFMA16(a,b,c) __builtin_amdgcn_mfma_f32_16x16x32_f16(a,b,c,0,0,0)
#define RBAR() do { __builtin_amdgcn_sched_barrier(0); __builtin_amdgcn_s_barrier(); __builtin_amdgcn_sched_barrier(0); } while (0)

// ---------------------------------------------------------------------------
// prep: weight fragments (fp16 hi/lo), combined biases, head output row
// ---------------------------------------------------------------------------
__global__ __launch_bounds__(256) void k_prep(
    const float* __restrict__ Wih_f, const float* __restrict__ Whh_f,
    const float* __restrict__ Wih_b, const float* __restrict__ Whh_b,
    const float* __restrict__ bih_f, const float* __restrict__ bhh_f,
    const float* __restrict__ bih_b, const float* __restrict__ bhh_b,
    const float* __restrict__ node, const float* __restrict__ bias,
    f16x8* __restrict__ Bfrag, float* __restrict__ bcomb, float* __restrict__ out)
{
  int gid = blockIdx.x*256 + threadIdx.x;
  if (gid < TOTF) {
    int lane = gid & 63;
    int s = gid >> 6;
    int nt = s % NT;  s /= NT;
    int kt = s % KT;  s /= KT;
    int term = s & 1; s >>= 1;
    int gemm = s & 1; s >>= 1;
    int dir  = s;
    int sec = nt / NQ, qq = nt - sec*NQ;
    int c = qq*16 + (lane & 15);
    int row = sec*Hc + c;
    const float* W = dir ? (gemm ? Whh_b : Wih_b) : (gemm ? Whh_f : Wih_f);
    f16x8 v;
#pragma unroll
    for (int e = 0; e < 8; ++e) {
      int k = kt*32 + (lane>>4)*8 + e;
      float wv = (c < Hc && k < Hc) ? W[row*Hc + k] : 0.f;
      _Float16 hi = (_Float16)wv;
      v[e] = term ? (_Float16)(wv - (float)hi) : hi;
    }
    Bfrag[gid] = v;
    return;
  }
  int i = gid - TOTF;
  if (i < 2560) {
    int dir = i / 1280; int r = i - dir*1280;
    int buf = r / 320, c = r - buf*320;
    const float* bih = dir ? bih_b : bih_f;
    const float* bhh = dir ? bhh_b : bhh_f;
    float v = 0.f;
    if (c < Hc) {
      if (buf == 0) v = bih[c] + bhh[c];
      else if (buf == 1) v = bih[Hc+c] + bhh[Hc+c];
      else if (buf == 2) v = bih[2*Hc+c];
      else v = bhh[2*Hc+c];
    }
    bcomb[i] = v;
    return;
  }
  i -= 2560;
  if (i < 600) {   // head row: out[0] = [message[0], message[0]]
    int c = (i < Hc) ? i : i - Hc;
    out[i] = fmaxf(node[c] + bias[c], 0.f);
  }
}

// ---------------------------------------------------------------------------
// shared helpers
// ---------------------------------------------------------------------------
__device__ __forceinline__ u32 f32_to_hl(float v) {
  union { _Float16 f; unsigned short u; } a, b;
  a.f = (_Float16)v;
  b.f = (_Float16)(v - (float)a.f);
  return (u32)a.u | ((u32)b.u << 16);
}

__device__ __forceinline__ float ntl1(const float* p) {
  return __builtin_nontemporal_load(p);
}
__device__ __forceinline__ float ntlh(const _Float16* p) {
  return (float)__builtin_nontemporal_load(p);
}
__device__ __forceinline__ f32x4 ntl4(const float* p) {
  return __builtin_nontemporal_load((const f32x4*)p);
}

// async global->LDS, 16 B per lane (dest = wave-uniform base + lane*16)
__device__ __forceinline__ void gll16(const void* g, void* l) {
  __builtin_amdgcn_global_load_lds(
      (const __attribute__((address_space(1))) u32*)g,
      (__attribute__((address_space(3))) u32*)l, 16, 0, 0);
}

// write h value (channel pair cE..cE+1, graph g<16) into M=16 A-fragment layout
__device__ __forceinline__ void afh_write(u32 (&buf)[2][KT][256],
                                          int l15, int g, int cE, u32 p, int lane) {
  u32 qv = (u32)__builtin_amdgcn_ds_bpermute((lane ^ 1) << 2, (int)p);
  int kt = cE >> 5;
  int dw = ((((cE >> 3) & 3) << 4) + g) * 4 + ((cE & 7) >> 1);
  if ((l15 & 1) == 0) buf[0][kt][dw] = (p & 0xFFFFu) | (qv << 16);
  else                buf[1][kt][dw] = (qv >> 16) | (p & 0xFFFF0000u);
}

__device__ __forceinline__ float sigf(float x) {
  return __builtin_amdgcn_rcpf(1.f + __expf(-x));
}
__device__ __forceinline__ float tanhfast(float x) {
  return 1.f - 2.f * __builtin_amdgcn_rcpf(__expf(2.f * x) + 1.f);
}

// ---------------------------------------------------------------------------
// k_xp: xp[row][dir][sec][304] (fp16) = relu(node[row]+bias) @ fp16(W_ih)^T
// ---------------------------------------------------------------------------
__global__ __launch_bounds__(640) void k_xp(
    const float* __restrict__ node, const float* __restrict__ bias,
    const f16x8* __restrict__ Bfrag, _Float16* __restrict__ xp, int Nrows)
{
  __shared__ __align__(16) u32 AfX[2][4][KT][256];
  int tid = threadIdx.x, w = tid >> 6, lane = tid & 63;
  int l15 = lane & 15, l4 = lane >> 4;
  int r0 = blockIdx.x * 64;

  int k8 = w*32 + (l4 << 3);
  float bb[8];
#pragma unroll
  for (int e = 0; e < 8; ++e) bb[e] = 0.f;
  if (k8 + 8 <= Hc) {
    f32x4 a = *(const f32x4*)&bias[k8];
    f32x4 b = *(const f32x4*)&bias[k8+4];
#pragma unroll
    for (int e = 0; e < 4; ++e) { bb[e] = a[e]; bb[e+4] = b[e]; }
  } else if (k8 < Hc) {
    f32x4 a = *(const f32x4*)&bias[k8];
#pragma unroll
    for (int e = 0; e < 4; ++e) bb[e] = a[e];
  }

#pragma unroll
  for (int mt = 0; mt < 4; ++mt) {
    int row = r0 + mt*16 + l15;
    float xv[8];
#pragma unroll
    for (int e = 0; e < 8; ++e) xv[e] = 0.f;
    if (row < Nrows) {
      const float* rp = node + (size_t)row * Hc + k8;
      if (k8 + 8 <= Hc) {
        f32x4 a = ntl4(rp);
        f32x4 b = ntl4(rp + 4);
#pragma unroll
        for (int e = 0; e < 4; ++e) {
          xv[e]   = fmaxf(a[e] + bb[e],   0.f);
          xv[e+4] = fmaxf(b[e] + bb[e+4], 0.f);
        }
      } else if (k8 < Hc) {
        f32x4 a = ntl4(rp);
#pragma unroll
        for (int e = 0; e < 4; ++e) xv[e] = fmaxf(a[e] + bb[e], 0.f);
      }
    }
    f16x8 vh, vl;
#pragma unroll
    for (int e = 0; e < 8; ++e) {
      vh[e] = (_Float16)xv[e];
      vl[e] = (_Float16)(xv[e] - (float)vh[e]);
    }
    *(f16x8*)&AfX[0][mt][w][lane*4] = vh;
    *(f16x8*)&AfX[1][mt][w][lane*4] = vl;
  }
  __syncthreads();

  int qv0 = w, qv1 = w + 10;
  int c0 = qv0*16 + l15, c1 = qv1*16 + l15;
  const f32x4 zz = {0.f, 0.f, 0.f, 0.f};

#pragma unroll 1
  for (int dir = 0; dir < 2; ++dir) {
    const f16x8* Bxh = Bfrag + (size_t)dir * PERDIR;

#pragma unroll 1
    for (int qi = 0; qi < 2; ++qi) {
      int qv = qi ? qv1 : qv0;
      int c  = qi ? c1  : c0;
      f32x4 acc[3][4];
#pragma unroll
      for (int sec = 0; sec < 3; ++sec)
#pragma unroll
        for (int mt = 0; mt < 4; ++mt) acc[sec][mt] = zz;

#pragma unroll 2
      for (int kt = 0; kt < KT; ++kt) {
        f16x8 axh[4], axl[4];
#pragma unroll
        for (int mt = 0; mt < 4; ++mt) {
          axh[mt] = *(const f16x8*)&AfX[0][mt][kt][lane*4];
          axl[mt] = *(const f16x8*)&AfX[1][mt][kt][lane*4];
        }
#pragma unroll
        for (int sec = 0; sec < 3; ++sec) {
          int nt = sec*NQ + qv;
          f16x8 bh = Bxh[(kt*NT + nt)*64 + lane];
#pragma unroll
          for (int mt = 0; mt < 4; ++mt) {
            acc[sec][mt] = MFMA16(axh[mt], bh, acc[sec][mt]);
            acc[sec][mt] = MFMA16(axl[mt], bh, acc[sec][mt]);
          }
        }
      }
      if (c < 304) {
#pragma unroll
        for (int sec = 0; sec < 3; ++sec)
#pragma unroll
          for (int mt = 0; mt < 4; ++mt)
#pragma unroll
            for (int j = 0; j < 4; ++j) {
              int row = r0 + mt*16 + (l4<<2) + j;
              if (row < Nrows)
                __builtin_nontemporal_store((_Float16)acc[sec][mt][j],
                    &xp[((size_t)row*2 + dir)*912 + sec*304 + c]);
            }
      }
    }
  }
}

// ---------------------------------------------------------------------------
// k_rec: producer/consumer with 4-slot half-kt ring and counted vmcnt
// (round-16 structure, verbatim; xp read as fp16).
// ---------------------------------------------------------------------------
__global__ __launch_bounds__(NTH) void k_rec(
    const float* __restrict__ node,
    const f16x8* __restrict__ Bfrag, const float* __restrict__ bcomb,
    const _Float16* __restrict__ xp,
    const int* __restrict__ starts, const int* __restrict__ sizes,
    float* __restrict__ out)
{
  __shared__ __align__(16) u32 Bbuf[4][7680];       // 4 x 30 KB half-kt slots
  __shared__ __align__(16) u32 AfH[2][KT][256];     // 20 KB, single buffer
  __shared__ int sst[16], ssz[16];

  int bid = blockIdx.x;
  int dir = (bid & 7) >= 4;                  // XCDs 0-3: forward, 4-7: backward
  int tslot = (bid & 3) + (bid >> 3) * 4;    // 0..127, bijective per dir
  int g0 = tslot * GB;

  int tid = threadIdx.x;
  int w = tid >> 6, lane = tid & 63;
  int l15 = lane & 15, l4 = lane >> 4;

  if (tid < 16) { sst[tid] = starts[g0 + tid]; ssz[tid] = sizes[g0 + tid]; }

  const f16x8* Bhh = Bfrag + (size_t)dir * PERDIR + 2*KT*NT*64;
  const f32x4 zz = {0.f, 0.f, 0.f, 0.f};

  bool prod = (w >= NCW);
  int pw = w - NCW;                          // producer wave id 0/1

  int qv0 = w, qv1 = w + 10;                 // consumer q-groups
  int c0 = qv0*16 + l15, c1 = qv1*16 + l15;

  const float* bc = bcomb + dir*1280;
  float bcr[2], bcz[2], bci[2], bch[2];
  float hreg0[4], hreg1[4];

// issue one half-unit U (15 frags per producer wave) into its ring slot
#define PISSUE(U) { \
    int kt_ = (U) >> 1, hf_ = (U) & 1; \
    char* sb_ = ((char*)&Bbuf[0][0]) + ((U) & 3) * 30720; \
    _Pragma("unroll") \
    for (int ff = 0; ff < 15; ++ff) { \
      int fi_ = pw*15 + ff; \
      int q3_ = fi_ / 3; \
      int sec_ = fi_ - 3*q3_; \
      const f16x8* gs_ = Bhh + ((size_t)(kt_*NT + sec_*NQ + hf_*10 + q3_))*64 + lane; \
      gll16((const void*)gs_, (void*)(sb_ + fi_*1024)); \
    } }

  if (prod) {
    PISSUE(0) PISSUE(1) PISSUE(2)
    asm volatile("s_waitcnt vmcnt(30)" ::: "memory");  // unit 0 resident
  } else {
    bcr[0] = bc[c0];       bcr[1] = bc[c1];
    bcz[0] = bc[320 + c0]; bcz[1] = bc[320 + c1];
    bci[0] = bc[640 + c0]; bci[1] = bc[640 + c1];
    bch[0] = bc[960 + c0]; bch[1] = bc[960 + c1];
  }
  asm volatile("s_waitcnt lgkmcnt(0)" ::: "memory");
  RBAR();   // sst/ssz + unit 0 published

  if (!prod) {
    // ---- h0: per-graph max-pool of raw node, lane-local ----
#pragma unroll
    for (int j = 0; j < 4; ++j) {
      int g = (l4<<2) + j;
      int st = sst[g], sz = ssz[g];
      float m0 = -1e30f, m1 = 0.f;
      for (int i = 0; i < sz; ++i)           // c0 always < Hc
        m0 = fmaxf(m0, ntl1(&node[(size_t)(st + i) * Hc + c0]));
      if (c1 < Hc) {
        m1 = -1e30f;
        for (int i = 0; i < sz; ++i)
          m1 = fmaxf(m1, ntl1(&node[(size_t)(st + i) * Hc + c1]));
      }
      hreg0[j] = m0;
      hreg1[j] = m1;
      afh_write(AfH, l15, g, c0 & ~1, f32_to_hl(m0), lane);
      afh_write(AfH, l15, g, c1 & ~1, f32_to_hl(m1), lane);
    }
  }
  asm volatile("s_waitcnt lgkmcnt(0)" ::: "memory");
  RBAR();   // AfH(h0) published

#pragma unroll 1
  for (int t = 0; t < Ld; ++t) {
    int time = dir ? (Ld-1-t) : t;

    // consumer: xvv prefetch (latency hides under the window sweep)
    float xvv0[3][4], xvv1[3][4];
    if (!prod) {
#pragma unroll
      for (int j = 0; j < 4; ++j) {
        int g = (l4<<2) + j;
        bool v = (time < ssz[g]);
        const _Float16* xb = xp + ((size_t)(sst[g] + time)*2 + dir)*912 + c0;
#pragma unroll
        for (int sec = 0; sec < 3; ++sec)
          xvv0[sec][j] = v ? ntlh(xb + sec*304) : 0.f;
        bool v1 = (c1 < 304) && v;
        const _Float16* xb1 = xp + ((size_t)(sst[g] + time)*2 + dir)*912 + c1;
#pragma unroll
        for (int sec = 0; sec < 3; ++sec)
          xvv1[sec][j] = v1 ? ntlh(xb1 + sec*304) : 0.f;
      }
    }

    f32x4 ha0[3] = { zz, zz, zz };
    f32x4 ha1[3] = { zz, zz, zz };

#pragma unroll 1
    for (int kt = 0; kt < KT; ++kt) {
      // ---- window A: unit 2kt (half 0 -> ha0) ----
      if (prod) {
        int u3 = 2*kt + 3; if (u3 >= 20) u3 -= 20;
        PISSUE(u3)
        asm volatile("s_waitcnt vmcnt(30)" ::: "memory");
      } else {
        const char* bbase = (const char*)&Bbuf[0][0] + ((2*kt) & 3)*30720 + lane*16;
        f16x8 ah = *(const f16x8*)&AfH[0][kt][lane*4];
        f16x8 al = *(const f16x8*)&AfH[1][kt][lane*4];
#pragma unroll
        for (int sec = 0; sec < 3; ++sec) {
          f16x8 b0 = *(const f16x8*)(bbase + (w*3 + sec)*1024);
          ha0[sec] = MFMA16(ah, b0, ha0[sec]);
          ha0[sec] = MFMA16(al, b0, ha0[sec]);
        }
      }
      RBAR();   // unit 2kt+1 published; slot (2kt)&3 reads done

      // ---- window B: unit 2kt+1 (half 1 -> ha1) ----
      if (prod) {
        int u4 = 2*kt + 4; if (u4 >= 20) u4 -= 20;
        PISSUE(u4)
        asm volatile("s_waitcnt vmcnt(30)" ::: "memory");
      } else {
        const char* bbase = (const char*)&Bbuf[0][0] + ((2*kt+1) & 3)*30720 + lane*16;
        f16x8 ah = *(const f16x8*)&AfH[0][kt][lane*4];
        f16x8 al = *(const f16x8*)&AfH[1][kt][lane*4];
#pragma unroll
        for (int sec = 0; sec < 3; ++sec) {
          f16x8 b1 = *(const f16x8*)(bbase + (w*3 + sec)*1024);
          ha1[sec] = MFMA16(ah, b1, ha1[sec]);
          ha1[sec] = MFMA16(al, b1, ha1[sec]);
        }
      }
      RBAR();   // unit 2kt+2 published; slot (2kt+1)&3 reads done
    }

    // ---- epilogue (consumers): gates + h update + AfH rewrite ----
    if (!prod) {
#pragma unroll
      for (int j = 0; j < 4; ++j) {
        int g = (l4<<2) + j;
        float rr = sigf(ha0[0][j] + xvv0[0][j] + bcr[0]);
        float zi = sigf(ha0[1][j] + xvv0[1][j] + bcz[0]);
        float nn = tanhfast(xvv0[2][j] + bci[0] + rr * (ha0[2][j] + bch[0]));
        float h_ = (1.f - zi) * nn + zi * hreg0[j];
        hreg0[j] = h_;
        if (time < ssz[g])
          __builtin_nontemporal_store(h_,
              &out[(size_t)(1 + sst[g] + time)*600 + dir*Hc + c0]);
        afh_write(AfH, l15, g, c0 & ~1, f32_to_hl(h_), lane);

        float rr1 = sigf(ha1[0][j] + xvv1[0][j] + bcr[1]);
        float zi1 = sigf(ha1[1][j] + xvv1[1][j] + bcz[1]);
        float nn1 = tanhfast(xvv1[2][j] + bci[1] + rr1 * (ha1[2][j] + bch[1]));
        float h1 = (1.f - zi1) * nn1 + zi1 * hreg1[j];
        if (c1 >= Hc) h1 = 0.f;
        hreg1[j] = h1;
        if (c1 < Hc && time < ssz[g])
          __builtin_nontemporal_store(h1,
              &out[(size_t)(1 + sst[g] + time)*600 + dir*Hc + c1]);
        afh_write(AfH, l15, g, c1 & ~1, f32_to_hl(h1), lane);
      }
    }
    asm volatile("s_waitcnt lgkmcnt(0)" ::: "memory");
    RBAR();   // new AfH published for next step
  }
#undef PISSUE
}

// ---------------------------------------------------------------------------
// k_rec_fb: monolithic fallback (ws too small) — round-3 design, M=16
// ---------------------------------------------------------------------------
__global__ __launch_bounds__(640) void k_rec_fb(
    const float* __restrict__ node, const float* __restrict__ bias,
    const f16x8* __restrict__ Bfrag, const float* __restrict__ bcomb,
    const int* __restrict__ starts, const int* __restrict__ sizes,
    float* __restrict__ out)
{
  __shared__ __align__(16) u32 AfX[2][4][KT][256];
  __shared__ __align__(16) u32 AfH[2][2][KT][256];
  __shared__ int sst[GBF], ssz[GBF];

  int bid = blockIdx.x;
  int dir = (bid & 7) >= 4;
  int tslot = (bid & 3) + (bid >> 3) * 4;
  int g0 = tslot * GBF;

  int tid = threadIdx.x;
  int w = tid >> 6, lane = tid & 63;
  int l15 = lane & 15, l4 = lane >> 4;

  if (tid < GBF) { sst[tid] = starts[g0 + tid]; ssz[tid] = sizes[g0 + tid]; }
  __syncthreads();

  int qv[2] = { w, w + 10 };
  int cq[2] = { qv[0]*16 + l15, qv[1]*16 + l15 };

  const float* bc = bcomb + dir*1280;
  float bcr[2], bcz[2], bci[2], bch[2];
#pragma unroll
  for (int qi = 0; qi < 2; ++qi) {
    int c = cq[qi];
    bcr[qi] = bc[c]; bcz[qi] = bc[320 + c]; bci[qi] = bc[640 + c]; bch[qi] = bc[960 + c];
  }
  int stj[4], szj[4];
#pragma unroll
  for (int j = 0; j < 4; ++j) { stj[j] = sst[(l4<<2)+j]; szj[j] = ssz[(l4<<2)+j]; }
  int stG = sst[l15], szG = ssz[l15];

  const f16x8* Bd  = Bfrag + (size_t)dir * PERDIR;
  const f16x8* Bxh = Bd;
  const f16x8* Bxl = Bd + KT*NT*64;
  const f16x8* Bhh = Bd + 2*KT*NT*64;
  const f16x8* Bhl = Bd + 3*KT*NT*64;
  const f32x4 zz = {0.f, 0.f, 0.f, 0.f};

  int k8 = w*32 + (l4<<3);
  float bb[8];
#pragma unroll
  for (int e = 0; e < 8; ++e) bb[e] = 0.f;
  if (k8 + 8 <= Hc) {
    f32x4 a = *(const f32x4*)&bias[k8];
    f32x4 b = *(const f32x4*)&bias[k8+4];
#pragma unroll
    for (int e = 0; e < 4; ++e) { bb[e] = a[e]; bb[e+4] = b[e]; }
  } else if (k8 < Hc) {
    f32x4 a = *(const f32x4*)&bias[k8];
#pragma unroll
    for (int e = 0; e < 4; ++e) bb[e] = a[e];
  }

  float hreg[2][4];
#pragma unroll
  for (int qi = 0; qi < 2; ++qi) {
    int c = cq[qi];
#pragma unroll
    for (int j = 0; j < 4; ++j) {
      float m = 0.f;
      if (c < Hc) {
        m = -1e30f;
        int st = stj[j], sz = szj[j];
        for (int i = 0; i < sz; ++i)
          m = fmaxf(m, node[(size_t)(st + i) * Hc + c]);
      }
      hreg[qi][j] = m;
      afh_write(AfH[0], l15, (l4<<2)+j, c & ~1, f32_to_hl(m), lane);
    }
  }

#define HSTEPF(S) { \
    constexpr int CUR = (S)&1; \
    constexpr int NXT = CUR^1; \
    f32x4 ha[2][3]; \
    _Pragma("unroll") \
    for (int qi = 0; qi < 2; ++qi) { ha[qi][0] = zz; ha[qi][1] = zz; ha[qi][2] = zz; } \
    _Pragma("unroll 2") \
    for (int kt = 0; kt < KT; ++kt) { \
      f16x8 ahh = *(const f16x8*)&AfH[CUR][0][kt][lane*4]; \
      f16x8 ahl = *(const f16x8*)&AfH[CUR][1][kt][lane*4]; \
      _Pragma("unroll") \
      for (int qi = 0; qi < 2; ++qi) { \
        _Pragma("unroll") \
        for (int sec = 0; sec < 3; ++sec) { \
          int nt = sec*NQ + qv[qi]; \
          f16x8 bh = Bhh[(kt*NT + nt)*64 + lane]; \
          f16x8 bl = Bhl[(kt*NT + nt)*64 + lane]; \
          ha[qi][sec] = MFMA16(ahh, bh, ha[qi][sec]); \
          ha[qi][sec] = MFMA16(ahh, bl, ha[qi][sec]); \
          ha[qi][sec] = MFMA16(ahl, bh, ha[qi][sec]); \
        } \
      } \
    } \
    int tt = 4*T + (S); \
    int time = dir ? (Ld-1-tt) : tt; \
    _Pragma("unroll") \
    for (int qi = 0; qi < 2; ++qi) { \
      int c = cq[qi]; \
      _Pragma("unroll") \
      for (int j = 0; j < 4; ++j) { \
        float rp_ = ha[qi][0][j] + xa[qi][0][S][j] + bcr[qi]; \
        float zp_ = ha[qi][1][j] + xa[qi][1][S][j] + bcz[qi]; \
        float r_ = 1.f/(1.f + __expf(-rp_)); \
        float z_ = 1.f/(1.f + __expf(-zp_)); \
        float n_ = tanhf(xa[qi][2][S][j] + bci[qi] + r_*(ha[qi][2][j] + bch[qi])); \
        float h_ = (1.f - z_)*n_ + z_*hreg[qi][j]; \
        if (c >= Hc) h_ = 0.f; \
        hreg[qi][j] = h_; \
        if (c < Hc && time < szj[j]) \
          out[(size_t)(1 + stj[j] + time)*600 + dir*Hc + c] = h_; \
        afh_write(AfH[NXT], l15, (l4<<2)+j, c & ~1, f32_to_hl(h_), lane); \
      } \
    } \
    __syncthreads(); \
  }

#pragma unroll 1
  for (int T = 0; T < Ld/4; ++T) {
#pragma unroll
    for (int s = 0; s < 4; ++s) {
      int tt = 4*T + s;
      int time = dir ? (Ld-1-tt) : tt;
      float xv[8];
#pragma unroll
      for (int e = 0; e < 8; ++e) xv[e] = 0.f;
      if (time < szG) {
        const float* rp = node + (size_t)(stG + time) * Hc + k8;
        if (k8 + 8 <= Hc) {
          f32x4 a = *(const f32x4*)rp;
          f32x4 b = *(const f32x4*)(rp + 4);
#pragma unroll
          for (int e = 0; e < 4; ++e) {
            xv[e]   = fmaxf(a[e] + bb[e],   0.f);
            xv[e+4] = fmaxf(b[e] + bb[e+4], 0.f);
          }
        } else if (k8 < Hc) {
          f32x4 a = *(const f32x4*)rp;
#pragma unroll
          for (int e = 0; e < 4; ++e) xv[e] = fmaxf(a[e] + bb[e], 0.f);
        }
      }
      f16x8 vh, vl;
#pragma unroll
      for (int e = 0; e < 8; ++e) {
        vh[e] = (_Float16)xv[e];
        vl[e] = (_Float16)(xv[e] - (float)vh[e]);
      }
      *(f16x8*)&AfX[0][s][w][lane*4] = vh;
      *(f16x8*)&AfX[1][s][w][lane*4] = vl;
    }
    __syncthreads();

    f32x4 xa[2][3][4];
#pragma unroll
    for (int qi = 0; qi < 2; ++qi)
#pragma unroll
      for (int sec = 0; sec < 3; ++sec)
#pragma unroll
        for (int mt = 0; mt < 4; ++mt) xa[qi][sec][mt] = zz;

#pragma unroll 1
    for (int kt = 0; kt < KT; ++kt) {
      f16x8 axh[4], axl[4];
#pragma unroll
      for (int mt = 0; mt < 4; ++mt) {
        axh[mt] = *(const f16x8*)&AfX[0][mt][kt][lane*4];
        axl[mt] = *(const f16x8*)&AfX[1][mt][kt][lane*4];
      }
#pragma unroll
      for (int qi = 0; qi < 2; ++qi) {
#pragma unroll
        for (int sec = 0; sec < 3; ++sec) {
          int nt = sec*NQ + qv[qi];
          f16x8 bh = Bxh[(kt*NT + nt)*64 + lane];
          f16x8 bl = Bxl[(kt*NT + nt)*64 + lane];
#pragma unroll
          for (int mt = 0; mt < 4; ++mt) {
            xa[qi][sec][mt] = MFMA16(axh[mt], bh, xa[qi][sec][mt]);
            xa[qi][sec][mt] = MFMA16(axh[mt], bl, xa[qi][sec][mt]);
            xa[qi][sec][mt] = MFMA16(axl[mt], bh, xa[qi][sec][mt]);
          }
        }
      }
    }

    HSTEPF(0)
    HSTEPF(1)
    HSTEPF(2)
    HSTEPF(3)
  }
#undef HSTEPF
}

extern "C" void kernel_launch(void* const* d_in, const int* in_sizes, int n_in,
                              void* d_out, int out_size, void* d_ws, size_t ws_size,
                              hipStream_t stream) {
  const float* node  = (const float*)d_in[0];
  const float* bias  = (const float*)d_in[1];
  const float* Wih_f = (const float*)d_in[2];
  const float* Whh_f = (const float*)d_in[3];
  const float* bih_f = (const float*)d_in[4];
  const float* bhh_f = (const float*)d_in[5];
  const float* Wih_b = (const float*)d_in[6];
  const float* Whh_b = (const float*)d_in[7];
  const float* bih_b = (const float*)d_in[8];
  const float* bhh_b = (const float*)d_in[9];
  const int* starts  = (const int*)d_in[10];
  const int* sizes   = (const int*)d_in[11];

  int ngr = in_sizes[10];          // 2048 graphs
  int N = in_sizes[0] / Hc;        // 98273 node rows

  float* out = (float*)d_out;
  f16x8* Bfrag = (f16x8*)d_ws;
  float* bcomb = (float*)((char*)d_ws + (size_t)TOTF*16);
  size_t xp_off = (size_t)TOTF*16 + 2560*4;
  size_t need = xp_off + (size_t)N * 1824 * 2;   // xp is fp16 now

  int prep_threads = TOTF + 2560 + 600;
  hipLaunchKernelGGL(k_prep, dim3((prep_threads + 255)/256), dim3(256), 0, stream,
                     Wih_f, Whh_f, Wih_b, Whh_b, bih_f, bhh_f, bih_b, bhh_b,
                     node, bias, Bfrag, bcomb, out);

  if (ws_size >= need && (ngr % GB) == 0) {
    _Float16* xp = (_Float16*)((char*)d_ws + xp_off);
    int nxb = (N + 63) / 64;
    hipLaunchKernelGGL(k_xp, dim3(nxb), dim3(640), 0, stream,
                       node, bias, Bfrag, xp, N);
    int ntile = ngr / GB;          // 128 tiles of 16 graphs -> grid 256
    hipLaunchKernelGGL(k_rec, dim3(2*ntile), dim3(NTH), 0, stream,
                       node, Bfrag, bcomb, xp, starts, sizes, out);
  } else {
    int ntilef = ngr / GBF;        // 128 tiles of 16 graphs
    hipLaunchKernelGGL(k_rec_fb, dim3(2*ntilef), dim3(640), 0, stream,
                       node, bias, Bfrag, bcomb, starts, sizes, out);
  }
}

// Round 19
// 1363.138 us; speedup vs baseline: 1.4807x; 1.4807x over previous
//
#include <hip/hip_runtime.h>
#include <math.h>

#define Hc 300
#define Ld 64
#define GB 16        // graphs per block (k_rec)
#define GBF 16       // graphs per block (fallback kernel)
#define KT 10        // K tiles of 32 (K padded 300->320)
#define NQ 20        // 16-col q-groups per gate section (N padded 300->320)
#define NT 60        // total n-tiles = 3 sections * NQ
#define PERDIR (2*2*KT*NT*64)   // f16x8 frags per dir = 153600
#define TOTF   (2*PERDIR)       // 307200 total
#define NCW 10       // consumer waves
#define NTH 768      // 10 consumer + 2 producer waves

typedef _Float16 f16x8 __attribute__((ext_vector_type(8)));
typedef float f32x4 __attribute__((ext_vector_type(4)));
typedef unsigned int u32;

#define MFMA16(a,b,c) __builtin_amdgcn_mfma_f32_16x16x32_f16(a,b,c,0,0,0)
#define RBAR() do { __builtin_amdgcn_sched_barrier(0); __builtin_amdgcn_s_barrier(); __builtin_amdgcn_sched_barrier(0); } while (0)

// ---------------------------------------------------------------------------
// prep: weight fragments (fp16 hi/lo), combined biases, head output row
// ---------------------------------------------------------------------------
__global__ __launch_bounds__(256) void k_prep(
    const float* __restrict__ Wih_f, const float* __restrict__ Whh_f,
    const float* __restrict__ Wih_b, const float* __restrict__ Whh_b,
    const float* __restrict__ bih_f, const float* __restrict__ bhh_f,
    const float* __restrict__ bih_b, const float* __restrict__ bhh_b,
    const float* __restrict__ node, const float* __restrict__ bias,
    f16x8* __restrict__ Bfrag, float* __restrict__ bcomb, float* __restrict__ out)
{
  int gid = blockIdx.x*256 + threadIdx.x;
  if (gid < TOTF) {
    int lane = gid & 63;
    int s = gid >> 6;
    int nt = s % NT;  s /= NT;
    int kt = s % KT;  s /= KT;
    int term = s & 1; s >>= 1;
    int gemm = s & 1; s >>= 1;
    int dir  = s;
    int sec = nt / NQ, qq = nt - sec*NQ;
    int c = qq*16 + (lane & 15);
    int row = sec*Hc + c;
    const float* W = dir ? (gemm ? Whh_b : Wih_b) : (gemm ? Whh_f : Wih_f);
    f16x8 v;
#pragma unroll
    for (int e = 0; e < 8; ++e) {
      int k = kt*32 + (lane>>4)*8 + e;
      float wv = (c < Hc && k < Hc) ? W[row*Hc + k] : 0.f;
      _Float16 hi = (_Float16)wv;
      v[e] = term ? (_Float16)(wv - (float)hi) : hi;
    }
    Bfrag[gid] = v;
    return;
  }
  int i = gid - TOTF;
  if (i < 2560) {
    int dir = i / 1280; int r = i - dir*1280;
    int buf = r / 320, c = r - buf*320;
    const float* bih = dir ? bih_b : bih_f;
    const float* bhh = dir ? bhh_b : bhh_f;
    float v = 0.f;
    if (c < Hc) {
      if (buf == 0) v = bih[c] + bhh[c];
      else if (buf == 1) v = bih[Hc+c] + bhh[Hc+c];
      else if (buf == 2) v = bih[2*Hc+c];
      else v = bhh[2*Hc+c];
    }
    bcomb[i] = v;
    return;
  }
  i -= 2560;
  if (i < 600) {   // head row: out[0] = [message[0], message[0]]
    int c = (i < Hc) ? i : i - Hc;
    out[i] = fmaxf(node[c] + bias[c], 0.f);
  }
}

// ---------------------------------------------------------------------------
// shared helpers
// ---------------------------------------------------------------------------
__device__ __forceinline__ u32 f32_to_hl(float v) {
  union { _Float16 f; unsigned short u; } a, b;
  a.f = (_Float16)v;
  b.f = (_Float16)(v - (float)a.f);
  return (u32)a.u | ((u32)b.u << 16);
}

__device__ __forceinline__ float ntl1(const float* p) {
  return __builtin_nontemporal_load(p);
}
__device__ __forceinline__ f32x4 ntl4(const float* p) {
  return __builtin_nontemporal_load((const f32x4*)p);
}

// async global->LDS, 16 B per lane (dest = wave-uniform base + lane*16)
__device__ __forceinline__ void gll16(const void* g, void* l) {
  __builtin_amdgcn_global_load_lds(
      (const __attribute__((address_space(1))) u32*)g,
      (__attribute__((address_space(3))) u32*)l, 16, 0, 0);
}

// write h value (channel pair cE..cE+1, graph g<16) into M=16 A-fragment layout
__device__ __forceinline__ void afh_write(u32 (&buf)[2][KT][256],
                                          int l15, int g, int cE, u32 p, int lane) {
  u32 qv = (u32)__builtin_amdgcn_ds_bpermute((lane ^ 1) << 2, (int)p);
  int kt = cE >> 5;
  int dw = ((((cE >> 3) & 3) << 4) + g) * 4 + ((cE & 7) >> 1);
  if ((l15 & 1) == 0) buf[0][kt][dw] = (p & 0xFFFFu) | (qv << 16);
  else                buf[1][kt][dw] = (qv >> 16) | (p & 0xFFFF0000u);
}

__device__ __forceinline__ float sigf(float x) {
  return __builtin_amdgcn_rcpf(1.f + __expf(-x));
}
__device__ __forceinline__ float tanhfast(float x) {
  return 1.f - 2.f * __builtin_amdgcn_rcpf(__expf(2.f * x) + 1.f);
}

// ---------------------------------------------------------------------------
// k_xp: xp[row][dir][sec][304] = relu(node[row]+bias) @ fp16(W_ih)^T
// (round-12 version, f32 output)
// ---------------------------------------------------------------------------
__global__ __launch_bounds__(640) void k_xp(
    const float* __restrict__ node, const float* __restrict__ bias,
    const f16x8* __restrict__ Bfrag, float* __restrict__ xp, int Nrows)
{
  __shared__ __align__(16) u32 AfX[2][4][KT][256];
  int tid = threadIdx.x, w = tid >> 6, lane = tid & 63;
  int l15 = lane & 15, l4 = lane >> 4;
  int r0 = blockIdx.x * 64;

  int k8 = w*32 + (l4 << 3);
  float bb[8];
#pragma unroll
  for (int e = 0; e < 8; ++e) bb[e] = 0.f;
  if (k8 + 8 <= Hc) {
    f32x4 a = *(const f32x4*)&bias[k8];
    f32x4 b = *(const f32x4*)&bias[k8+4];
#pragma unroll
    for (int e = 0; e < 4; ++e) { bb[e] = a[e]; bb[e+4] = b[e]; }
  } else if (k8 < Hc) {
    f32x4 a = *(const f32x4*)&bias[k8];
#pragma unroll
    for (int e = 0; e < 4; ++e) bb[e] = a[e];
  }

#pragma unroll
  for (int mt = 0; mt < 4; ++mt) {
    int row = r0 + mt*16 + l15;
    float xv[8];
#pragma unroll
    for (int e = 0; e < 8; ++e) xv[e] = 0.f;
    if (row < Nrows) {
      const float* rp = node + (size_t)row * Hc + k8;
      if (k8 + 8 <= Hc) {
        f32x4 a = ntl4(rp);
        f32x4 b = ntl4(rp + 4);
#pragma unroll
        for (int e = 0; e < 4; ++e) {
          xv[e]   = fmaxf(a[e] + bb[e],   0.f);
          xv[e+4] = fmaxf(b[e] + bb[e+4], 0.f);
        }
      } else if (k8 < Hc) {
        f32x4 a = ntl4(rp);
#pragma unroll
        for (int e = 0; e < 4; ++e) xv[e] = fmaxf(a[e] + bb[e], 0.f);
      }
    }
    f16x8 vh, vl;
#pragma unroll
    for (int e = 0; e < 8; ++e) {
      vh[e] = (_Float16)xv[e];
      vl[e] = (_Float16)(xv[e] - (float)vh[e]);
    }
    *(f16x8*)&AfX[0][mt][w][lane*4] = vh;
    *(f16x8*)&AfX[1][mt][w][lane*4] = vl;
  }
  __syncthreads();

  int qv0 = w, qv1 = w + 10;
  int c0 = qv0*16 + l15, c1 = qv1*16 + l15;
  const f32x4 zz = {0.f, 0.f, 0.f, 0.f};

#pragma unroll 1
  for (int dir = 0; dir < 2; ++dir) {
    const f16x8* Bxh = Bfrag + (size_t)dir * PERDIR;

#pragma unroll 1
    for (int qi = 0; qi < 2; ++qi) {
      int qv = qi ? qv1 : qv0;
      int c  = qi ? c1  : c0;
      f32x4 acc[3][4];
#pragma unroll
      for (int sec = 0; sec < 3; ++sec)
#pragma unroll
        for (int mt = 0; mt < 4; ++mt) acc[sec][mt] = zz;

#pragma unroll 2
      for (int kt = 0; kt < KT; ++kt) {
        f16x8 axh[4], axl[4];
#pragma unroll
        for (int mt = 0; mt < 4; ++mt) {
          axh[mt] = *(const f16x8*)&AfX[0][mt][kt][lane*4];
          axl[mt] = *(const f16x8*)&AfX[1][mt][kt][lane*4];
        }
#pragma unroll
        for (int sec = 0; sec < 3; ++sec) {
          int nt = sec*NQ + qv;
          f16x8 bh = Bxh[(kt*NT + nt)*64 + lane];
#pragma unroll
          for (int mt = 0; mt < 4; ++mt) {
            acc[sec][mt] = MFMA16(axh[mt], bh, acc[sec][mt]);
            acc[sec][mt] = MFMA16(axl[mt], bh, acc[sec][mt]);
          }
        }
      }
      if (c < 304) {
#pragma unroll
        for (int sec = 0; sec < 3; ++sec)
#pragma unroll
          for (int mt = 0; mt < 4; ++mt)
#pragma unroll
            for (int j = 0; j < 4; ++j) {
              int row = r0 + mt*16 + (l4<<2) + j;
              if (row < Nrows)
                __builtin_nontemporal_store(acc[sec][mt][j],
                    &xp[((size_t)row*2 + dir)*912 + sec*304 + c]);
            }
      }
    }
  }
}

// ---------------------------------------------------------------------------
// k_rec: producer/consumer with 4-slot half-kt ring and counted vmcnt
// (round-16 structure, verbatim).
// ---------------------------------------------------------------------------
__global__ __launch_bounds__(NTH) void k_rec(
    const float* __restrict__ node,
    const f16x8* __restrict__ Bfrag, const float* __restrict__ bcomb,
    const float* __restrict__ xp,
    const int* __restrict__ starts, const int* __restrict__ sizes,
    float* __restrict__ out)
{
  __shared__ __align__(16) u32 Bbuf[4][7680];       // 4 x 30 KB half-kt slots
  __shared__ __align__(16) u32 AfH[2][KT][256];     // 20 KB, single buffer
  __shared__ int sst[16], ssz[16];

  int bid = blockIdx.x;
  int dir = (bid & 7) >= 4;                  // XCDs 0-3: forward, 4-7: backward
  int tslot = (bid & 3) + (bid >> 3) * 4;    // 0..127, bijective per dir
  int g0 = tslot * GB;

  int tid = threadIdx.x;
  int w = tid >> 6, lane = tid & 63;
  int l15 = lane & 15, l4 = lane >> 4;

  if (tid < 16) { sst[tid] = starts[g0 + tid]; ssz[tid] = sizes[g0 + tid]; }

  const f16x8* Bhh = Bfrag + (size_t)dir * PERDIR + 2*KT*NT*64;
  const f32x4 zz = {0.f, 0.f, 0.f, 0.f};

  bool prod = (w >= NCW);
  int pw = w - NCW;                          // producer wave id 0/1

  int qv0 = w, qv1 = w + 10;                 // consumer q-groups
  int c0 = qv0*16 + l15, c1 = qv1*16 + l15;

  const float* bc = bcomb + dir*1280;
  float bcr[2], bcz[2], bci[2], bch[2];
  float hreg0[4], hreg1[4];

// issue one half-unit U (15 frags per producer wave) into its ring slot
#define PISSUE(U) { \
    int kt_ = (U) >> 1, hf_ = (U) & 1; \
    char* sb_ = ((char*)&Bbuf[0][0]) + ((U) & 3) * 30720; \
    _Pragma("unroll") \
    for (int ff = 0; ff < 15; ++ff) { \
      int fi_ = pw*15 + ff; \
      int q3_ = fi_ / 3; \
      int sec_ = fi_ - 3*q3_; \
      const f16x8* gs_ = Bhh + ((size_t)(kt_*NT + sec_*NQ + hf_*10 + q3_))*64 + lane; \
      gll16((const void*)gs_, (void*)(sb_ + fi_*1024)); \
    } }

  if (prod) {
    PISSUE(0) PISSUE(1) PISSUE(2)
    asm volatile("s_waitcnt vmcnt(30)" ::: "memory");  // unit 0 resident
  } else {
    bcr[0] = bc[c0];       bcr[1] = bc[c1];
    bcz[0] = bc[320 + c0]; bcz[1] = bc[320 + c1];
    bci[0] = bc[640 + c0]; bci[1] = bc[640 + c1];
    bch[0] = bc[960 + c0]; bch[1] = bc[960 + c1];
  }
  asm volatile("s_waitcnt lgkmcnt(0)" ::: "memory");
  RBAR();   // sst/ssz + unit 0 published

  if (!prod) {
    // ---- h0: per-graph max-pool of raw node, lane-local ----
#pragma unroll
    for (int j = 0; j < 4; ++j) {
      int g = (l4<<2) + j;
      int st = sst[g], sz = ssz[g];
      float m0 = -1e30f, m1 = 0.f;
      for (int i = 0; i < sz; ++i)           // c0 always < Hc
        m0 = fmaxf(m0, ntl1(&node[(size_t)(st + i) * Hc + c0]));
      if (c1 < Hc) {
        m1 = -1e30f;
        for (int i = 0; i < sz; ++i)
          m1 = fmaxf(m1, ntl1(&node[(size_t)(st + i) * Hc + c1]));
      }
      hreg0[j] = m0;
      hreg1[j] = m1;
      afh_write(AfH, l15, g, c0 & ~1, f32_to_hl(m0), lane);
      afh_write(AfH, l15, g, c1 & ~1, f32_to_hl(m1), lane);
    }
  }
  asm volatile("s_waitcnt lgkmcnt(0)" ::: "memory");
  RBAR();   // AfH(h0) published

#pragma unroll 1
  for (int t = 0; t < Ld; ++t) {
    int time = dir ? (Ld-1-t) : t;

    // consumer: xvv prefetch (latency hides under the window sweep)
    float xvv0[3][4], xvv1[3][4];
    if (!prod) {
#pragma unroll
      for (int j = 0; j < 4; ++j) {
        int g = (l4<<2) + j;
        bool v = (time < ssz[g]);
        const float* xb = xp + ((size_t)(sst[g] + time)*2 + dir)*912 + c0;
#pragma unroll
        for (int sec = 0; sec < 3; ++sec)
          xvv0[sec][j] = v ? ntl1(xb + sec*304) : 0.f;
        bool v1 = (c1 < 304) && v;
        const float* xb1 = xp + ((size_t)(sst[g] + time)*2 + dir)*912 + c1;
#pragma unroll
        for (int sec = 0; sec < 3; ++sec)
          xvv1[sec][j] = v1 ? ntl1(xb1 + sec*304) : 0.f;
      }
    }

    f32x4 ha0[3] = { zz, zz, zz };
    f32x4 ha1[3] = { zz, zz, zz };

#pragma unroll 1
    for (int kt = 0; kt < KT; ++kt) {
      // ---- window A: unit 2kt (half 0 -> ha0) ----
      if (prod) {
        int u3 = 2*kt + 3; if (u3 >= 20) u3 -= 20;
        PISSUE(u3)
        asm volatile("s_waitcnt vmcnt(30)" ::: "memory");
      } else {
        const char* bbase = (const char*)&Bbuf[0][0] + ((2*kt) & 3)*30720 + lane*16;
        f16x8 ah = *(const f16x8*)&AfH[0][kt][lane*4];
        f16x8 al = *(const f16x8*)&AfH[1][kt][lane*4];
#pragma unroll
        for (int sec = 0; sec < 3; ++sec) {
          f16x8 b0 = *(const f16x8*)(bbase + (w*3 + sec)*1024);
          ha0[sec] = MFMA16(ah, b0, ha0[sec]);
          ha0[sec] = MFMA16(al, b0, ha0[sec]);
        }
      }
      RBAR();   // unit 2kt+1 published; slot (2kt)&3 reads done

      // ---- window B: unit 2kt+1 (half 1 -> ha1) ----
      if (prod) {
        int u4 = 2*kt + 4; if (u4 >= 20) u4 -= 20;
        PISSUE(u4)
        asm volatile("s_waitcnt vmcnt(30)" ::: "memory");
      } else {
        const char* bbase = (const char*)&Bbuf[0][0] + ((2*kt+1) & 3)*30720 + lane*16;
        f16x8 ah = *(const f16x8*)&AfH[0][kt][lane*4];
        f16x8 al = *(const f16x8*)&AfH[1][kt][lane*4];
#pragma unroll
        for (int sec = 0; sec < 3; ++sec) {
          f16x8 b1 = *(const f16x8*)(bbase + (w*3 + sec)*1024);
          ha1[sec] = MFMA16(ah, b1, ha1[sec]);
          ha1[sec] = MFMA16(al, b1, ha1[sec]);
        }
      }
      RBAR();   // unit 2kt+2 published; slot (2kt+1)&3 reads done
    }

    // ---- epilogue (consumers): gates + h update + AfH rewrite ----
    if (!prod) {
#pragma unroll
      for (int j = 0; j < 4; ++j) {
        int g = (l4<<2) + j;
        float rr = sigf(ha0[0][j] + xvv0[0][j] + bcr[0]);
        float zi = sigf(ha0[1][j] + xvv0[1][j] + bcz[0]);
        float nn = tanhfast(xvv0[2][j] + bci[0] + rr * (ha0[2][j] + bch[0]));
        float h_ = (1.f - zi) * nn + zi * hreg0[j];
        hreg0[j] = h_;
        if (time < ssz[g])
          __builtin_nontemporal_store(h_,
              &out[(size_t)(1 + sst[g] + time)*600 + dir*Hc + c0]);
        afh_write(AfH, l15, g, c0 & ~1, f32_to_hl(h_), lane);

        float rr1 = sigf(ha1[0][j] + xvv1[0][j] + bcr[1]);
        float zi1 = sigf(ha1[1][j] + xvv1[1][j] + bcz[1]);
        float nn1 = tanhfast(xvv1[2][j] + bci[1] + rr1 * (ha1[2][j] + bch[1]));
        float h1 = (1.f - zi1) * nn1 + zi1 * hreg1[j];
        if (c1 >= Hc) h1 = 0.f;
        hreg1[j] = h1;
        if (c1 < Hc && time < ssz[g])
          __builtin_nontemporal_store(h1,
              &out[(size_t)(1 + sst[g] + time)*600 + dir*Hc + c1]);
        afh_write(AfH, l15, g, c1 & ~1, f32_to_hl(h1), lane);
      }
    }
    asm volatile("s_waitcnt lgkmcnt(0)" ::: "memory");
    RBAR();   // new AfH published for next step
  }
#undef PISSUE
}

// ---------------------------------------------------------------------------
// k_rec_fb: monolithic fallback (ws too small) — round-3 design, M=16
// ---------------------------------------------------------------------------
__global__ __launch_bounds__(640) void k_rec_fb(
    const float* __restrict__ node, const float* __restrict__ bias,
    const f16x8* __restrict__ Bfrag, const float* __restrict__ bcomb,
    const int* __restrict__ starts, const int* __restrict__ sizes,
    float* __restrict__ out)
{
  __shared__ __align__(16) u32 AfX[2][4][KT][256];
  __shared__ __align__(16) u32 AfH[2][2][KT][256];
  __shared__ int sst[GBF], ssz[GBF];

  int bid = blockIdx.x;
  int dir = (bid & 7) >= 4;
  int tslot = (bid & 3) + (bid >> 3) * 4;
  int g0 = tslot * GBF;

  int tid = threadIdx.x;
  int w = tid >> 6, lane = tid & 63;
  int l15 = lane & 15, l4 = lane >> 4;

  if (tid < GBF) { sst[tid] = starts[g0 + tid]; ssz[tid] = sizes[g0 + tid]; }
  __syncthreads();

  int qv[2] = { w, w + 10 };
  int cq[2] = { qv[0]*16 + l15, qv[1]*16 + l15 };

  const float* bc = bcomb + dir*1280;
  float bcr[2], bcz[2], bci[2], bch[2];
#pragma unroll
  for (int qi = 0; qi < 2; ++qi) {
    int c = cq[qi];
    bcr[qi] = bc[c]; bcz[qi] = bc[320 + c]; bci[qi] = bc[640 + c]; bch[qi] = bc[960 + c];
  }
  int stj[4], szj[4];
#pragma unroll
  for (int j = 0; j < 4; ++j) { stj[j] = sst[(l4<<2)+j]; szj[j] = ssz[(l4<<2)+j]; }
  int stG = sst[l15], szG = ssz[l15];

  const f16x8* Bd  = Bfrag + (size_t)dir * PERDIR;
  const f16x8* Bxh = Bd;
  const f16x8* Bxl = Bd + KT*NT*64;
  const f16x8* Bhh = Bd + 2*KT*NT*64;
  const f16x8* Bhl = Bd + 3*KT*NT*64;
  const f32x4 zz = {0.f, 0.f, 0.f, 0.f};

  int k8 = w*32 + (l4<<3);
  float bb[8];
#pragma unroll
  for (int e = 0; e < 8; ++e) bb[e] = 0.f;
  if (k8 + 8 <= Hc) {
    f32x4 a = *(const f32x4*)&bias[k8];
    f32x4 b = *(const f32x4*)&bias[k8+4];
#pragma unroll
    for (int e = 0; e < 4; ++e) { bb[e] = a[e]; bb[e+4] = b[e]; }
  } else if (k8 < Hc) {
    f32x4 a = *(const f32x4*)&bias[k8];
#pragma unroll
    for (int e = 0; e < 4; ++e) bb[e] = a[e];
  }

  float hreg[2][4];
#pragma unroll
  for (int qi = 0; qi < 2; ++qi) {
    int c = cq[qi];
#pragma unroll
    for (int j = 0; j < 4; ++j) {
      float m = 0.f;
      if (c < Hc) {
        m = -1e30f;
        int st = stj[j], sz = szj[j];
        for (int i = 0; i < sz; ++i)
          m = fmaxf(m, node[(size_t)(st + i) * Hc + c]);
      }
      hreg[qi][j] = m;
      afh_write(AfH[0], l15, (l4<<2)+j, c & ~1, f32_to_hl(m), lane);
    }
  }

#define HSTEPF(S) { \
    constexpr int CUR = (S)&1; \
    constexpr int NXT = CUR^1; \
    f32x4 ha[2][3]; \
    _Pragma("unroll") \
    for (int qi = 0; qi < 2; ++qi) { ha[qi][0] = zz; ha[qi][1] = zz; ha[qi][2] = zz; } \
    _Pragma("unroll 2") \
    for (int kt = 0; kt < KT; ++kt) { \
      f16x8 ahh = *(const f16x8*)&AfH[CUR][0][kt][lane*4]; \
      f16x8 ahl = *(const f16x8*)&AfH[CUR][1][kt][lane*4]; \
      _Pragma("unroll") \
      for (int qi = 0; qi < 2; ++qi) { \
        _Pragma("unroll") \
        for (int sec = 0; sec < 3; ++sec) { \
          int nt = sec*NQ + qv[qi]; \
          f16x8 bh = Bhh[(kt*NT + nt)*64 + lane]; \
          f16x8 bl = Bhl[(kt*NT + nt)*64 + lane]; \
          ha[qi][sec] = MFMA16(ahh, bh, ha[qi][sec]); \
          ha[qi][sec] = MFMA16(ahh, bl, ha[qi][sec]); \
          ha[qi][sec] = MFMA16(ahl, bh, ha[qi][sec]); \
        } \
      } \
    } \
    int tt = 4*T + (S); \
    int time = dir ? (Ld-1-tt) : tt; \
    _Pragma("unroll") \
    for (int qi = 0; qi < 2; ++qi) { \
      int c = cq[qi]; \
      _Pragma("unroll") \
      for (int j = 0; j < 4; ++j) { \
        float rp_ = ha[qi][0][j] + xa[qi][0][S][j] + bcr[qi]; \
        float zp_ = ha[qi][1][j] + xa[qi][1][S][j] + bcz[qi]; \
        float r_ = 1.f/(1.f + __expf(-rp_)); \
        float z_ = 1.f/(1.f + __expf(-zp_)); \
        float n_ = tanhf(xa[qi][2][S][j] + bci[qi] + r_*(ha[qi][2][j] + bch[qi])); \
        float h_ = (1.f - z_)*n_ + z_*hreg[qi][j]; \
        if (c >= Hc) h_ = 0.f; \
        hreg[qi][j] = h_; \
        if (c < Hc && time < szj[j]) \
          out[(size_t)(1 + stj[j] + time)*600 + dir*Hc + c] = h_; \
        afh_write(AfH[NXT], l15, (l4<<2)+j, c & ~1, f32_to_hl(h_), lane); \
      } \
    } \
    __syncthreads(); \
  }

#pragma unroll 1
  for (int T = 0; T < Ld/4; ++T) {
#pragma unroll
    for (int s = 0; s < 4; ++s) {
      int tt = 4*T + s;
      int time = dir ? (Ld-1-tt) : tt;
      float xv[8];
#pragma unroll
      for (int e = 0; e < 8; ++e) xv[e] = 0.f;
      if (time < szG) {
        const float* rp = node + (size_t)(stG + time) * Hc + k8;
        if (k8 + 8 <= Hc) {
          f32x4 a = *(const f32x4*)rp;
          f32x4 b = *(const f32x4*)(rp + 4);
#pragma unroll
          for (int e = 0; e < 4; ++e) {
            xv[e]   = fmaxf(a[e] + bb[e],   0.f);
            xv[e+4] = fmaxf(b[e] + bb[e+4], 0.f);
          }
        } else if (k8 < Hc) {
          f32x4 a = *(const f32x4*)rp;
#pragma unroll
          for (int e = 0; e < 4; ++e) xv[e] = fmaxf(a[e] + bb[e], 0.f);
        }
      }
      f16x8 vh, vl;
#pragma unroll
      for (int e = 0; e < 8; ++e) {
        vh[e] = (_Float16)xv[e];
        vl[e] = (_Float16)(xv[e] - (float)vh[e]);
      }
      *(f16x8*)&AfX[0][s][w][lane*4] = vh;
      *(f16x8*)&AfX[1][s][w][lane*4] = vl;
    }
    __syncthreads();

    f32x4 xa[2][3][4];
#pragma unroll
    for (int qi = 0; qi < 2; ++qi)
#pragma unroll
      for (int sec = 0; sec < 3; ++sec)
#pragma unroll
        for (int mt = 0; mt < 4; ++mt) xa[qi][sec][mt] = zz;

#pragma unroll 1
    for (int kt = 0; kt < KT; ++kt) {
      f16x8 axh[4], axl[4];
#pragma unroll
      for (int mt = 0; mt < 4; ++mt) {
        axh[mt] = *(const f16x8*)&AfX[0][mt][kt][lane*4];
        axl[mt] = *(const f16x8*)&AfX[1][mt][kt][lane*4];
      }
#pragma unroll
      for (int qi = 0; qi < 2; ++qi) {
#pragma unroll
        for (int sec = 0; sec < 3; ++sec) {
          int nt = sec*NQ + qv[qi];
          f16x8 bh = Bxh[(kt*NT + nt)*64 + lane];
          f16x8 bl = Bxl[(kt*NT + nt)*64 + lane];
#pragma unroll
          for (int mt = 0; mt < 4; ++mt) {
            xa[qi][sec][mt] = MFMA16(axh[mt], bh, xa[qi][sec][mt]);
            xa[qi][sec][mt] = MFMA16(axh[mt], bl, xa[qi][sec][mt]);
            xa[qi][sec][mt] = MFMA16(axl[mt], bh, xa[qi][sec][mt]);
          }
        }
      }
    }

    HSTEPF(0)
    HSTEPF(1)
    HSTEPF(2)
    HSTEPF(3)
  }
#undef HSTEPF
}

extern "C" void kernel_launch(void* const* d_in, const int* in_sizes, int n_in,
                              void* d_out, int out_size, void* d_ws, size_t ws_size,
                              hipStream_t stream) {
  const float* node  = (const float*)d_in[0];
  const float* bias  = (const float*)d_in[1];
  const float* Wih_f = (const float*)d_in[2];
  const float* Whh_f = (const float*)d_in[3];
  const float* bih_f = (const float*)d_in[4];
  const float* bhh_f = (const float*)d_in[5];
  const float* Wih_b = (const float*)d_in[6];
  const float* Whh_b = (const float*)d_in[7];
  const float* bih_b = (const float*)d_in[8];
  const float* bhh_b = (const float*)d_in[9];
  const int* starts  = (const int*)d_in[10];
  const int* sizes   = (const int*)d_in[11];

  int ngr = in_sizes[10];          // 2048 graphs
  int N = in_sizes[0] / Hc;        // 98273 node rows

  float* out = (float*)d_out;
  f16x8* Bfrag = (f16x8*)d_ws;
  float* bcomb = (float*)((char*)d_ws + (size_t)TOTF*16);
  size_t xp_off = (size_t)TOTF*16 + 2560*4;
  size_t need = xp_off + (size_t)N * 1824 * 4;

  int prep_threads = TOTF + 2560 + 600;
  hipLaunchKernelGGL(k_prep, dim3((prep_threads + 255)/256), dim3(256), 0, stream,
                     Wih_f, Whh_f, Wih_b, Whh_b, bih_f, bhh_f, bih_b, bhh_b,
                     node, bias, Bfrag, bcomb, out);

  if (ws_size >= need && (ngr % GB) == 0) {
    float* xp = (float*)((char*)d_ws + xp_off);
    int nxb = (N + 63) / 64;
    hipLaunchKernelGGL(k_xp, dim3(nxb), dim3(640), 0, stream,
                       node, bias, Bfrag, xp, N);
    int ntile = ngr / GB;          // 128 tiles of 16 graphs -> grid 256
    hipLaunchKernelGGL(k_rec, dim3(2*ntile), dim3(NTH), 0, stream,
                       node, Bfrag, bcomb, xp, starts, sizes, out);
  } else {
    int ntilef = ngr / GBF;        // 128 tiles of 16 graphs
    hipLaunchKernelGGL(k_rec_fb, dim3(2*ntilef), dim3(640), 0, stream,
                       node, bias, Bfrag, bcomb, starts, sizes, out);
  }
}